// Round 4
// baseline (1397.338 us; speedup 1.0000x reference)
//
#include <hip/hip_runtime.h>
#include <hip/hip_bf16.h>
#include <cstddef>

// ---------------- problem constants ----------------
#define NTOK   64
#define CDIM   192
#define ODIM   576
#define HEADS  6
#define SCALE  0.17677669529663687f   // 1/sqrt(32)

#define WQ_ELEMS (ODIM*CDIM)
#define WP_ELEMS (CDIM*CDIM)

typedef __attribute__((ext_vector_type(8))) short bf16x8;
typedef __attribute__((ext_vector_type(4))) short bf16x4;
typedef __attribute__((ext_vector_type(4))) float f32x4;

static __device__ __forceinline__ unsigned short f2b(float f) {
    __hip_bfloat16 h = __float2bfloat16(f);
    return __builtin_bit_cast(unsigned short, h);
}

// 64B-row tiles (Q/K slabs)
static __device__ __forceinline__ char* swz64(char* base, int row, int b) {
    return base + row * 64 + (b ^ (((row >> 1) & 3) << 4));
}
// 128B-row tiles (V, P slabs)
static __device__ __forceinline__ char* swz128(char* base, int row, int b) {
    return base + ((row * 128 + b) ^ ((row & 7) << 4));
}
// 384B-row tile (AO staging in proj kernel)
static __device__ __forceinline__ char* swz384(char* base, int row, int b) {
    return base + ((row * 384 + b) ^ ((row & 7) << 4));
}

// ---------------- prep: fp32 weights -> bf16 (scale folded into W_q) ----------------
__global__ __launch_bounds__(256)
void prep_weights(const float* __restrict__ qkv_w, const float* __restrict__ proj_w,
                  unsigned short* __restrict__ wq, unsigned short* __restrict__ wp)
{
    int i = blockIdx.x * 256 + threadIdx.x;
    if (i < WQ_ELEMS) {
        float v = qkv_w[i];
        if (i < CDIM * CDIM) v *= SCALE;
        wq[i] = f2b(v);
    }
    if (i < WP_ELEMS) wp[i] = f2b(proj_w[i]);
}

// ---------------- kernel A: QKV + attention, one WAVE per (window, head) ----------------
// Wave-private 12KB LDS slab; no __syncthreads anywhere. AO (pre-proj) -> d_out fp32.
__global__ __launch_bounds__(256, 3)
void attn_per_head(const float* __restrict__ x,
                   const float* __restrict__ mask,
                   const unsigned short* __restrict__ wq,
                   const float* __restrict__ qkv_b,
                   const float* __restrict__ bias_table,
                   float* __restrict__ ao)
{
    __shared__ __align__(16) char smem[49152];   // 12KB per wave
    const int t    = threadIdx.x;
    const int wvid = t >> 6;
    const int l    = t & 63;
    const int lo   = l & 15;
    const int hi   = l >> 4;

    // XCD-chunked swizzle: all 6 head-waves of a window land on one XCD (L2 reuse).
    const int bid  = blockIdx.x;                     // nwg = 6144, 6144 % 8 == 0
    const int cpx  = gridDim.x >> 3;                 // 768
    const int swzb = (bid & 7) * cpx + (bid >> 3);
    const int pair = swzb * 4 + wvid;                // (w,h), h-fastest
    const int w    = pair / 6;
    const int h    = pair - w * 6;

    char* slab = smem + wvid * 12288;
    char* Qh = slab;            // [64 n][32 d] bf16
    char* Kh = slab + 4096;     // [64 m][32 d]
    char* Vh = slab + 8192;     // Vt [32 d][64 m]
    char* Ph = slab;            // [64 n][64 m] overlays Q+K after QK^T

    const float* xw = x + (size_t)w * (NTOK * CDIM);
    const int tq = 2 * h, tk = 12 + 2 * h, tv = 24 + 2 * h;

    // ---- pass 1a: Q,K tiles (swapped operands: D[o][n]) ----
    f32x4 aq[2][4] = {}, ak[2][4] = {};
    for (int ks = 0; ks < 6; ++ks) {
        bf16x8 xf[4];
        #pragma unroll
        for (int nt = 0; nt < 4; ++nt) {
            const float* p = xw + (nt * 16 + lo) * CDIM + ks * 32 + hi * 8;
            float4 v0 = *(const float4*)p;
            float4 v1 = *(const float4*)(p + 4);
            bf16x8 pk;
            pk[0] = (short)f2b(v0.x); pk[1] = (short)f2b(v0.y);
            pk[2] = (short)f2b(v0.z); pk[3] = (short)f2b(v0.w);
            pk[4] = (short)f2b(v1.x); pk[5] = (short)f2b(v1.y);
            pk[6] = (short)f2b(v1.z); pk[7] = (short)f2b(v1.w);
            xf[nt] = pk;
        }
        bf16x8 wqf[2], wkf[2];
        #pragma unroll
        for (int j = 0; j < 2; ++j) {
            wqf[j] = *(const bf16x8*)(const void*)(wq + ((tq + j) * 16 + lo) * CDIM + ks * 32 + hi * 8);
            wkf[j] = *(const bf16x8*)(const void*)(wq + ((tk + j) * 16 + lo) * CDIM + ks * 32 + hi * 8);
        }
        #pragma unroll
        for (int j = 0; j < 2; ++j)
            #pragma unroll
            for (int nt = 0; nt < 4; ++nt) {
                aq[j][nt] = __builtin_amdgcn_mfma_f32_16x16x32_bf16(wqf[j], xf[nt], aq[j][nt], 0, 0, 0);
                ak[j][nt] = __builtin_amdgcn_mfma_f32_16x16x32_bf16(wkf[j], xf[nt], ak[j][nt], 0, 0, 0);
            }
    }
    // store Q,K (+bias) as packed b64
    #pragma unroll
    for (int j = 0; j < 2; ++j) {
        float4 bq = *(const float4*)(qkv_b + (tq + j) * 16 + hi * 4);
        float4 bk = *(const float4*)(qkv_b + (tk + j) * 16 + hi * 4);
        float bqs[4] = {bq.x * SCALE, bq.y * SCALE, bq.z * SCALE, bq.w * SCALE};
        float bks[4] = {bk.x, bk.y, bk.z, bk.w};
        #pragma unroll
        for (int nt = 0; nt < 4; ++nt) {
            int n = nt * 16 + lo;
            bf16x4 pq, pk2;
            #pragma unroll
            for (int r = 0; r < 4; ++r) {
                pq[r]  = (short)f2b(aq[j][nt][r] + bqs[r]);
                pk2[r] = (short)f2b(ak[j][nt][r] + bks[r]);
            }
            *(bf16x4*)swz64(Qh, n, j * 32 + hi * 8) = pq;
            *(bf16x4*)swz64(Kh, n, j * 32 + hi * 8) = pk2;
        }
    }

    // ---- pass 1b: V tiles (normal orientation: D[n][d]) ----
    f32x4 av[4][2] = {};
    for (int ks = 0; ks < 6; ++ks) {
        bf16x8 xf[4];
        #pragma unroll
        for (int nt = 0; nt < 4; ++nt) {
            const float* p = xw + (nt * 16 + lo) * CDIM + ks * 32 + hi * 8;
            float4 v0 = *(const float4*)p;
            float4 v1 = *(const float4*)(p + 4);
            bf16x8 pk;
            pk[0] = (short)f2b(v0.x); pk[1] = (short)f2b(v0.y);
            pk[2] = (short)f2b(v0.z); pk[3] = (short)f2b(v0.w);
            pk[4] = (short)f2b(v1.x); pk[5] = (short)f2b(v1.y);
            pk[6] = (short)f2b(v1.z); pk[7] = (short)f2b(v1.w);
            xf[nt] = pk;
        }
        bf16x8 wvf[2];
        #pragma unroll
        for (int j = 0; j < 2; ++j)
            wvf[j] = *(const bf16x8*)(const void*)(wq + ((tv + j) * 16 + lo) * CDIM + ks * 32 + hi * 8);
        #pragma unroll
        for (int nt = 0; nt < 4; ++nt)
            #pragma unroll
            for (int j = 0; j < 2; ++j)
                av[nt][j] = __builtin_amdgcn_mfma_f32_16x16x32_bf16(xf[nt], wvf[j], av[nt][j], 0, 0, 0);
    }
    #pragma unroll
    for (int nt = 0; nt < 4; ++nt)
        #pragma unroll
        for (int j = 0; j < 2; ++j) {
            float bv = qkv_b[(tv + j) * 16 + lo];
            bf16x4 pv;
            #pragma unroll
            for (int r = 0; r < 4; ++r) pv[r] = (short)f2b(av[nt][j][r] + bv);
            *(bf16x4*)swz128(Vh, j * 16 + lo, (nt * 16 + hi * 4) * 2) = pv;
        }
    asm volatile("s_waitcnt lgkmcnt(0)" ::: "memory");

    // ---- QK^T + bias + mask (C-init) ----
    const float* maskW = mask + (size_t)w * (NTOK * NTOK);
    f32x4 cs[4][4];
    #pragma unroll
    for (int mt = 0; mt < 4; ++mt) {
        int m = mt * 16 + lo;
        int i2 = m >> 3, j2 = m & 7;
        #pragma unroll
        for (int nt = 0; nt < 4; ++nt)
            #pragma unroll
            for (int r = 0; r < 4; ++r) {
                int n = nt * 16 + hi * 4 + r;
                int i1 = n >> 3, j1 = n & 7;
                cs[nt][mt][r] = bias_table[((i1 - i2 + 7) * 15 + (j1 - j2 + 7)) * HEADS + h]
                              + maskW[n * 64 + m];
            }
    }
    {
        bf16x8 qa[4], kb[4];
        #pragma unroll
        for (int nt = 0; nt < 4; ++nt) qa[nt] = *(const bf16x8*)swz64(Qh, nt * 16 + lo, hi * 16);
        #pragma unroll
        for (int mt = 0; mt < 4; ++mt) kb[mt] = *(const bf16x8*)swz64(Kh, mt * 16 + lo, hi * 16);
        #pragma unroll
        for (int nt = 0; nt < 4; ++nt)
            #pragma unroll
            for (int mt = 0; mt < 4; ++mt)
                cs[nt][mt] = __builtin_amdgcn_mfma_f32_16x16x32_bf16(qa[nt], kb[mt], cs[nt][mt], 0, 0, 0);
    }

    // ---- softmax; P -> slab (overlays Q/K; wave-private so only lgkmcnt order needed) ----
    float inv[4][4];
    #pragma unroll
    for (int nt = 0; nt < 4; ++nt)
        #pragma unroll
        for (int r = 0; r < 4; ++r) {
            float mx = fmaxf(fmaxf(cs[nt][0][r], cs[nt][1][r]),
                             fmaxf(cs[nt][2][r], cs[nt][3][r]));
            mx = fmaxf(mx, __shfl_xor(mx, 1));
            mx = fmaxf(mx, __shfl_xor(mx, 2));
            mx = fmaxf(mx, __shfl_xor(mx, 4));
            mx = fmaxf(mx, __shfl_xor(mx, 8));
            float s = 0.f;
            #pragma unroll
            for (int mt = 0; mt < 4; ++mt) {
                float e = __expf(cs[nt][mt][r] - mx);
                cs[nt][mt][r] = e;
                s += e;
            }
            s += __shfl_xor(s, 1);
            s += __shfl_xor(s, 2);
            s += __shfl_xor(s, 4);
            s += __shfl_xor(s, 8);
            inv[nt][r] = 1.0f / s;
            int n = nt * 16 + hi * 4 + r;
            #pragma unroll
            for (int mt = 0; mt < 4; ++mt)
                *(unsigned short*)swz128(Ph, n, (mt * 16 + lo) * 2) = f2b(cs[nt][mt][r]);
        }
    asm volatile("s_waitcnt lgkmcnt(0)" ::: "memory");

    // ---- PV ----
    f32x4 co[4][2] = {};
    #pragma unroll
    for (int ks = 0; ks < 2; ++ks) {
        bf16x8 pa[4], vb[2];
        #pragma unroll
        for (int nt = 0; nt < 4; ++nt)
            pa[nt] = *(const bf16x8*)swz128(Ph, nt * 16 + lo, (ks * 32 + hi * 8) * 2);
        #pragma unroll
        for (int dt = 0; dt < 2; ++dt)
            vb[dt] = *(const bf16x8*)swz128(Vh, dt * 16 + lo, (ks * 32 + hi * 8) * 2);
        #pragma unroll
        for (int nt = 0; nt < 4; ++nt)
            #pragma unroll
            for (int dt = 0; dt < 2; ++dt)
                co[nt][dt] = __builtin_amdgcn_mfma_f32_16x16x32_bf16(pa[nt], vb[dt], co[nt][dt], 0, 0, 0);
    }

    // ---- AO -> global fp32 (64B segments), consumed by proj kernel ----
    float* aoW = ao + (size_t)w * (NTOK * CDIM);
    #pragma unroll
    for (int nt = 0; nt < 4; ++nt)
        #pragma unroll
        for (int dt = 0; dt < 2; ++dt)
            #pragma unroll
            for (int r = 0; r < 4; ++r) {
                int n = nt * 16 + hi * 4 + r;
                int d = dt * 16 + lo;
                aoW[n * CDIM + h * 32 + d] = co[nt][dt][r] * inv[nt][r];
            }
}

// ---------------- kernel B: out = AO . Wp^T + b, IN-PLACE on d_out ----------------
// Block stages its own 64 rows (fp32 -> bf16 LDS), accumulates fully, then
// overwrites exactly those rows. Safe: reads-before-writes within the block,
// no cross-block row sharing.
__global__ __launch_bounds__(256, 4)
void proj_inplace(float* __restrict__ buf,
                  const unsigned short* __restrict__ wp,
                  const float* __restrict__ proj_b)
{
    __shared__ __align__(16) char AO[24576];   // [64][192] bf16, swz384
    const int t  = threadIdx.x;
    const int wv = t >> 6;
    const int l  = t & 63;
    const int lo = l & 15;
    const int hi = l >> 4;

    float* rows = buf + (size_t)blockIdx.x * 64 * CDIM;

    // stage 64 rows coalesced, cvt to bf16
    #pragma unroll
    for (int i = 0; i < 6; ++i) {
        int c  = t + i * 256;                 // 1536 chunks of 8 floats
        int n  = c / 24;
        int cb = (c % 24) * 8;
        float4 v0 = *(const float4*)(rows + c * 8);
        float4 v1 = *(const float4*)(rows + c * 8 + 4);
        bf16x8 p;
        p[0] = (short)f2b(v0.x); p[1] = (short)f2b(v0.y);
        p[2] = (short)f2b(v0.z); p[3] = (short)f2b(v0.w);
        p[4] = (short)f2b(v1.x); p[5] = (short)f2b(v1.y);
        p[6] = (short)f2b(v1.z); p[7] = (short)f2b(v1.w);
        *(bf16x8*)swz384(AO, n, cb * 2) = p;
    }
    __syncthreads();

    // GEMM: wave wv owns 3 o-tiles
    f32x4 ac[3][4] = {};
    for (int ks = 0; ks < 6; ++ks) {
        bf16x8 aa[4], bb[3];
        #pragma unroll
        for (int nt = 0; nt < 4; ++nt)
            aa[nt] = *(const bf16x8*)swz384(AO, nt * 16 + lo, (ks * 32 + hi * 8) * 2);
        #pragma unroll
        for (int j = 0; j < 3; ++j) {
            int o2 = (wv * 3 + j) * 16 + lo;
            bb[j] = *(const bf16x8*)(const void*)(wp + o2 * CDIM + ks * 32 + hi * 8);
        }
        #pragma unroll
        for (int j = 0; j < 3; ++j)
            #pragma unroll
            for (int nt = 0; nt < 4; ++nt)
                ac[j][nt] = __builtin_amdgcn_mfma_f32_16x16x32_bf16(aa[nt], bb[j], ac[j][nt], 0, 0, 0);
    }
    #pragma unroll
    for (int j = 0; j < 3; ++j) {
        int o2 = (wv * 3 + j) * 16 + lo;
        float pb = proj_b[o2];
        #pragma unroll
        for (int nt = 0; nt < 4; ++nt)
            #pragma unroll
            for (int r = 0; r < 4; ++r) {
                int n = nt * 16 + hi * 4 + r;
                rows[n * CDIM + o2] = ac[j][nt][r] + pb;
            }
    }
}

extern "C" void kernel_launch(void* const* d_in, const int* in_sizes, int n_in,
                              void* d_out, int out_size, void* d_ws, size_t ws_size,
                              hipStream_t stream) {
    const float* x          = (const float*)d_in[0];
    const float* mask       = (const float*)d_in[1];
    const float* qkv_w      = (const float*)d_in[2];
    const float* qkv_b      = (const float*)d_in[3];
    const float* proj_w     = (const float*)d_in[4];
    const float* proj_b     = (const float*)d_in[5];
    const float* bias_table = (const float*)d_in[6];
    float* out = (float*)d_out;

    unsigned short* wq = (unsigned short*)d_ws;
    unsigned short* wp = wq + WQ_ELEMS;

    const int nW = in_sizes[0] / (NTOK * CDIM);   // 4096

    prep_weights<<<dim3((WQ_ELEMS + 255) / 256), dim3(256), 0, stream>>>(qkv_w, proj_w, wq, wp);

    // kernel A: one wave per (window, head); 4 waves/block
    const int nPairs = nW * HEADS;                // 24576
    attn_per_head<<<dim3(nPairs / 4), dim3(256), 0, stream>>>(
        x, mask, wq, qkv_b, bias_table, out);

    // kernel B: in-place proj over 64-row blocks
    proj_inplace<<<dim3(nW * NTOK / 64), dim3(256), 0, stream>>>(out, wp, proj_b);
}

// Round 5
// 501.935 us; speedup vs baseline: 2.7839x; 2.7839x over previous
//
#include <hip/hip_runtime.h>
#include <hip/hip_bf16.h>
#include <cstddef>

// ---------------- problem constants ----------------
#define NTOK   64
#define CDIM   192
#define HEADS  6
#define NTHR   384     // 6 waves; wave == head
#define SCALE  0.17677669529663687f   // 1/sqrt(32)

#define WQ_ELEMS (3*CDIM*CDIM)
#define WP_ELEMS (CDIM*CDIM)

// LDS: region A = X bf16 [64][192] swz384 (24576B) -> becomes AO after barrier.
//      region B = mask fp32 [64] rows, stride 68 floats (17408B), conflict-free reads.
#define OFF_MASK 24576
#define LDS_BYTES (24576 + 64*68*4)   // 41984 B static -> up to 3 blocks/CU by LDS

typedef __attribute__((ext_vector_type(8))) short bf16x8;
typedef __attribute__((ext_vector_type(4))) float f32x4;
typedef __attribute__((ext_vector_type(4))) unsigned int u32x4;

static __device__ __forceinline__ unsigned short f2b(float f) {
    __hip_bfloat16 h = __float2bfloat16(f);
    return __builtin_bit_cast(unsigned short, h);
}
static __device__ __forceinline__ char* swz384(char* base, int row, int b) {
    return base + ((row * 384 + b) ^ ((row & 7) << 4));
}

// pack f32x4 (+bias) into one bf16 quad (2 dwords)
static __device__ __forceinline__ uint2 packq4(f32x4 v, float4 b) {
    unsigned short e0 = f2b(v[0] + b.x), e1 = f2b(v[1] + b.y);
    unsigned short e2 = f2b(v[2] + b.z), e3 = f2b(v[3] + b.w);
    uint2 q; q.x = (unsigned)e0 | ((unsigned)e1 << 16);
             q.y = (unsigned)e2 | ((unsigned)e3 << 16);
    return q;
}
static __device__ __forceinline__ uint2 packqs(f32x4 v, float b) {
    unsigned short e0 = f2b(v[0] + b), e1 = f2b(v[1] + b);
    unsigned short e2 = f2b(v[2] + b), e3 = f2b(v[3] + b);
    uint2 q; q.x = (unsigned)e0 | ((unsigned)e1 << 16);
             q.y = (unsigned)e2 | ((unsigned)e3 << 16);
    return q;
}
static __device__ __forceinline__ uint2 packq0(f32x4 v) {
    unsigned short e0 = f2b(v[0]), e1 = f2b(v[1]);
    unsigned short e2 = f2b(v[2]), e3 = f2b(v[3]);
    uint2 q; q.x = (unsigned)e0 | ((unsigned)e1 << 16);
             q.y = (unsigned)e2 | ((unsigned)e3 << 16);
    return q;
}

// hi-group 4x4 quad transpose among lanes {lo, lo+16, lo+32, lo+48}.
// in: a = quad(hi), b = quad(4+hi).  out: oa = quad(2hi), ob = quad(2hi+1).
static __device__ __forceinline__ void p8(uint2 a, uint2 b, int lo, int hi,
                                          uint2& oa, uint2& ob) {
    int sA = lo + ((hi & 1) << 5);
    int sB = sA + 16;
    uint2 Aa, Ab, Ba, Bb;
    Aa.x = (unsigned)__shfl((int)a.x, sA); Aa.y = (unsigned)__shfl((int)a.y, sA);
    Ab.x = (unsigned)__shfl((int)b.x, sA); Ab.y = (unsigned)__shfl((int)b.y, sA);
    Ba.x = (unsigned)__shfl((int)a.x, sB); Ba.y = (unsigned)__shfl((int)a.y, sB);
    Bb.x = (unsigned)__shfl((int)b.x, sB); Bb.y = (unsigned)__shfl((int)b.y, sB);
    oa = (hi < 2) ? Aa : Ab;
    ob = (hi < 2) ? Ba : Bb;
}
static __device__ __forceinline__ bf16x8 mkfrag(uint2 oa, uint2 ob) {
    u32x4 u; u[0] = oa.x; u[1] = oa.y; u[2] = ob.x; u[3] = ob.y;
    return __builtin_bit_cast(bf16x8, u);
}

// ---------------- prep: fp32 weights -> bf16 (scale folded into W_q) ----------------
__global__ __launch_bounds__(256)
void prep_weights(const float* __restrict__ qkv_w, const float* __restrict__ proj_w,
                  unsigned short* __restrict__ wq, unsigned short* __restrict__ wp)
{
    int i = blockIdx.x * 256 + threadIdx.x;
    if (i < WQ_ELEMS) {
        float v = qkv_w[i];
        if (i < CDIM * CDIM) v *= SCALE;
        wq[i] = f2b(v);
    }
    if (i < WP_ELEMS) wp[i] = f2b(proj_w[i]);
}

// ---------------- fused window attention: block = window, wave = head ----------------
__global__ __launch_bounds__(NTHR, 3)
void win_attn(const float* __restrict__ x,
              const float* __restrict__ mask,
              const unsigned short* __restrict__ wq,
              const float* __restrict__ qkv_b,
              const unsigned short* __restrict__ wp,
              const float* __restrict__ proj_b,
              const float* __restrict__ bias_table,
              float* __restrict__ out)
{
    __shared__ __align__(16) char smem[LDS_BYTES];
    char*  XA    = smem;                          // X bf16 -> later AO bf16
    float* maskL = (float*)(smem + OFF_MASK);     // [64][68] fp32

    const int t  = threadIdx.x;
    const int w  = blockIdx.x;
    const int h  = t >> 6;
    const int l  = t & 63;
    const int lo = l & 15;
    const int hi = l >> 4;

    // ---- phase 0: stage X (fp32->bf16, swz384) + mask (stride-68 rows) ----
    const float* xw = x + (size_t)w * (NTOK * CDIM);
    #pragma unroll
    for (int it = 0; it < 4; ++it) {
        int c  = t + it * NTHR;            // 1536 chunks of 8 floats
        int n  = c / 24;
        int cb = (c % 24) * 8;
        float4 v0 = *(const float4*)(xw + c * 8);
        float4 v1 = *(const float4*)(xw + c * 8 + 4);
        bf16x8 p;
        p[0] = (short)f2b(v0.x); p[1] = (short)f2b(v0.y);
        p[2] = (short)f2b(v0.z); p[3] = (short)f2b(v0.w);
        p[4] = (short)f2b(v1.x); p[5] = (short)f2b(v1.y);
        p[6] = (short)f2b(v1.z); p[7] = (short)f2b(v1.w);
        *(bf16x8*)swz384(XA, n, cb * 2) = p;
    }
    const float* mw = mask + (size_t)w * (NTOK * NTOK);
    #pragma unroll
    for (int it = 0; it < 3; ++it) {
        int c = t + it * NTHR;             // 1024 float4
        if (c < 1024) {
            float4 v = *(const float4*)(mw + c * 4);
            int n  = c >> 4;
            int mq = (c & 15) * 4;
            *(float4*)(maskL + n * 68 + mq) = v;
        }
    }
    __syncthreads();

    // ---- phase 1a: Q,K of head h (swapped operands -> D[o][n], lane col = token) ----
    const int tq = 2 * h, tk = 12 + 2 * h, tv = 24 + 2 * h;
    f32x4 aq[2][4] = {}, ak[2][4] = {};
    for (int ks = 0; ks < 6; ++ks) {
        bf16x8 xf[4];
        #pragma unroll
        for (int nt = 0; nt < 4; ++nt)
            xf[nt] = *(const bf16x8*)swz384(XA, nt * 16 + lo, (ks * 32 + hi * 8) * 2);
        bf16x8 wqf[2], wkf[2];
        #pragma unroll
        for (int j = 0; j < 2; ++j) {
            wqf[j] = *(const bf16x8*)(const void*)(wq + ((tq + j) * 16 + lo) * CDIM + ks * 32 + hi * 8);
            wkf[j] = *(const bf16x8*)(const void*)(wq + ((tk + j) * 16 + lo) * CDIM + ks * 32 + hi * 8);
        }
        #pragma unroll
        for (int j = 0; j < 2; ++j)
            #pragma unroll
            for (int nt = 0; nt < 4; ++nt) {
                aq[j][nt] = __builtin_amdgcn_mfma_f32_16x16x32_bf16(wqf[j], xf[nt], aq[j][nt], 0, 0, 0);
                ak[j][nt] = __builtin_amdgcn_mfma_f32_16x16x32_bf16(wkf[j], xf[nt], ak[j][nt], 0, 0, 0);
            }
    }
    // transpose to A/B-frag layout: lane = token, 8 consecutive dims per lane
    bf16x8 Qf[4], Kf[4];
    {
        float4 bq0 = *(const float4*)(qkv_b + tq * 16 + hi * 4);
        float4 bq1 = *(const float4*)(qkv_b + (tq + 1) * 16 + hi * 4);
        float4 bk0 = *(const float4*)(qkv_b + tk * 16 + hi * 4);
        float4 bk1 = *(const float4*)(qkv_b + (tk + 1) * 16 + hi * 4);
        bq0.x *= SCALE; bq0.y *= SCALE; bq0.z *= SCALE; bq0.w *= SCALE;
        bq1.x *= SCALE; bq1.y *= SCALE; bq1.z *= SCALE; bq1.w *= SCALE;
        #pragma unroll
        for (int nt = 0; nt < 4; ++nt) {
            uint2 oa, ob;
            p8(packq4(aq[0][nt], bq0), packq4(aq[1][nt], bq1), lo, hi, oa, ob);
            Qf[nt] = mkfrag(oa, ob);
            p8(packq4(ak[0][nt], bk0), packq4(ak[1][nt], bk1), lo, hi, oa, ob);
            Kf[nt] = mkfrag(oa, ob);
        }
    }

    // ---- phase 1b: V of head h (normal orientation -> D[n][d], lane col = dim) ----
    f32x4 av[4][2] = {};
    for (int ks = 0; ks < 6; ++ks) {
        bf16x8 xf[4];
        #pragma unroll
        for (int nt = 0; nt < 4; ++nt)
            xf[nt] = *(const bf16x8*)swz384(XA, nt * 16 + lo, (ks * 32 + hi * 8) * 2);
        bf16x8 wvf[2];
        #pragma unroll
        for (int j = 0; j < 2; ++j)
            wvf[j] = *(const bf16x8*)(const void*)(wq + ((tv + j) * 16 + lo) * CDIM + ks * 32 + hi * 8);
        #pragma unroll
        for (int nt = 0; nt < 4; ++nt)
            #pragma unroll
            for (int j = 0; j < 2; ++j)
                av[nt][j] = __builtin_amdgcn_mfma_f32_16x16x32_bf16(xf[nt], wvf[j], av[nt][j], 0, 0, 0);
    }
    // transpose to PV B-frag: Vf[ks][dt] = V[m = 32ks+8hi..+7][d = 16dt+lo]
    bf16x8 Vf[2][2];
    {
        float bv0 = qkv_b[tv * 16 + lo];
        float bv1 = qkv_b[(tv + 1) * 16 + lo];
        #pragma unroll
        for (int dt = 0; dt < 2; ++dt) {
            float bv = dt ? bv1 : bv0;
            uint2 oa, ob;
            p8(packqs(av[0][dt], bv), packqs(av[1][dt], bv), lo, hi, oa, ob);
            Vf[0][dt] = mkfrag(oa, ob);
            p8(packqs(av[2][dt], bv), packqs(av[3][dt], bv), lo, hi, oa, ob);
            Vf[1][dt] = mkfrag(oa, ob);
        }
    }

    // ---- phase 2: S^T = K.Q^T + bias + mask (C-init). cs[mt][nt]: S[m][n], n = 16nt+lo ----
    f32x4 cs[4][4];
    #pragma unroll
    for (int nt = 0; nt < 4; ++nt) {
        int n  = nt * 16 + lo;
        int i1 = n >> 3, j1 = n & 7;
        #pragma unroll
        for (int mt = 0; mt < 4; ++mt) {
            float4 mv = *(const float4*)(maskL + n * 68 + mt * 16 + hi * 4);
            float mvr[4] = {mv.x, mv.y, mv.z, mv.w};
            #pragma unroll
            for (int r = 0; r < 4; ++r) {
                int m  = mt * 16 + hi * 4 + r;
                int i2 = m >> 3, j2 = m & 7;
                cs[mt][nt][r] = bias_table[((i1 - i2 + 7) * 15 + (j1 - j2 + 7)) * HEADS + h]
                              + mvr[r];
            }
        }
    }
    #pragma unroll
    for (int mt = 0; mt < 4; ++mt)
        #pragma unroll
        for (int nt = 0; nt < 4; ++nt)
            cs[mt][nt] = __builtin_amdgcn_mfma_f32_16x16x32_bf16(Kf[mt], Qf[nt], cs[mt][nt], 0, 0, 0);

    // ---- softmax over m (per n = 16nt+lo); fold 1/sum into P; transpose to A-frag ----
    bf16x8 Pf[2][4];
    #pragma unroll
    for (int nt = 0; nt < 4; ++nt) {
        float mx = cs[0][nt][0];
        #pragma unroll
        for (int mt = 0; mt < 4; ++mt)
            #pragma unroll
            for (int r = 0; r < 4; ++r) mx = fmaxf(mx, cs[mt][nt][r]);
        mx = fmaxf(mx, __shfl_xor(mx, 16));
        mx = fmaxf(mx, __shfl_xor(mx, 32));
        float s = 0.f;
        #pragma unroll
        for (int mt = 0; mt < 4; ++mt)
            #pragma unroll
            for (int r = 0; r < 4; ++r) {
                float e = __expf(cs[mt][nt][r] - mx);
                cs[mt][nt][r] = e;
                s += e;
            }
        s += __shfl_xor(s, 16);
        s += __shfl_xor(s, 32);
        float iv = 1.0f / s;
        #pragma unroll
        for (int mt = 0; mt < 4; ++mt)
            #pragma unroll
            for (int r = 0; r < 4; ++r) cs[mt][nt][r] *= iv;
        uint2 oa, ob;
        p8(packq0(cs[0][nt]), packq0(cs[1][nt]), lo, hi, oa, ob);
        Pf[0][nt] = mkfrag(oa, ob);
        p8(packq0(cs[2][nt]), packq0(cs[3][nt]), lo, hi, oa, ob);
        Pf[1][nt] = mkfrag(oa, ob);
    }

    // ---- phase 3: O = P.V ----
    f32x4 co[4][2] = {};
    #pragma unroll
    for (int nt = 0; nt < 4; ++nt)
        #pragma unroll
        for (int dt = 0; dt < 2; ++dt) {
            co[nt][dt] = __builtin_amdgcn_mfma_f32_16x16x32_bf16(Pf[0][nt], Vf[0][dt], co[nt][dt], 0, 0, 0);
            co[nt][dt] = __builtin_amdgcn_mfma_f32_16x16x32_bf16(Pf[1][nt], Vf[1][dt], co[nt][dt], 0, 0, 0);
        }

    __syncthreads();   // all waves done reading X -> safe to overlay AO

    // AO[n][h*32+d] bf16 into region A
    #pragma unroll
    for (int nt = 0; nt < 4; ++nt)
        #pragma unroll
        for (int dt = 0; dt < 2; ++dt)
            #pragma unroll
            for (int r = 0; r < 4; ++r) {
                int n = nt * 16 + hi * 4 + r;
                *(unsigned short*)swz384(XA, n, (h * 32 + dt * 16 + lo) * 2) =
                    f2b(co[nt][dt][r]);
            }
    __syncthreads();   // AO complete

    // ---- phase 4: out = AO . Wp^T + b (wave owns 2 o-tiles) ----
    f32x4 ac2[4][2] = {};
    for (int ks = 0; ks < 6; ++ks) {
        bf16x8 aa[4], bb[2];
        #pragma unroll
        for (int nt = 0; nt < 4; ++nt)
            aa[nt] = *(const bf16x8*)swz384(XA, nt * 16 + lo, (ks * 32 + hi * 8) * 2);
        #pragma unroll
        for (int j = 0; j < 2; ++j) {
            int o2 = (h * 2 + j) * 16 + lo;
            bb[j] = *(const bf16x8*)(const void*)(wp + o2 * CDIM + ks * 32 + hi * 8);
        }
        #pragma unroll
        for (int nt = 0; nt < 4; ++nt)
            #pragma unroll
            for (int j = 0; j < 2; ++j)
                ac2[nt][j] = __builtin_amdgcn_mfma_f32_16x16x32_bf16(aa[nt], bb[j], ac2[nt][j], 0, 0, 0);
    }
    float* outW = out + (size_t)w * (NTOK * CDIM);
    #pragma unroll
    for (int j = 0; j < 2; ++j) {
        int o2 = (h * 2 + j) * 16 + lo;
        float pb = proj_b[o2];
        #pragma unroll
        for (int nt = 0; nt < 4; ++nt)
            #pragma unroll
            for (int r = 0; r < 4; ++r) {
                int n = nt * 16 + hi * 4 + r;
                outW[n * CDIM + o2] = ac2[nt][j][r] + pb;
            }
    }
}

extern "C" void kernel_launch(void* const* d_in, const int* in_sizes, int n_in,
                              void* d_out, int out_size, void* d_ws, size_t ws_size,
                              hipStream_t stream) {
    const float* x          = (const float*)d_in[0];
    const float* mask       = (const float*)d_in[1];
    const float* qkv_w      = (const float*)d_in[2];
    const float* qkv_b      = (const float*)d_in[3];
    const float* proj_w     = (const float*)d_in[4];
    const float* proj_b     = (const float*)d_in[5];
    const float* bias_table = (const float*)d_in[6];
    float* out = (float*)d_out;

    unsigned short* wq = (unsigned short*)d_ws;
    unsigned short* wp = wq + WQ_ELEMS;

    const int nW = in_sizes[0] / (NTOK * CDIM);   // 4096

    prep_weights<<<dim3((WQ_ELEMS + 255) / 256), dim3(256), 0, stream>>>(qkv_w, proj_w, wq, wp);
    win_attn<<<dim3(nW), dim3(NTHR), 0, stream>>>(x, mask, wq, qkv_b, wp, proj_b,
                                                  bias_table, out);
}

// Round 6
// 390.924 us; speedup vs baseline: 3.5744x; 1.2840x over previous
//
#include <hip/hip_runtime.h>
#include <hip/hip_bf16.h>
#include <cstddef>

// ---------------- problem constants ----------------
#define NTOK   64
#define CDIM   192
#define HEADS  6
#define NTHR   768     // 12 waves; wave = (head, token-half)
#define SCALE  0.17677669529663687f   // 1/sqrt(32)

#define WQ_ELEMS (3*CDIM*CDIM)
#define WP_ELEMS (CDIM*CDIM)

// LDS byte offsets:
//  XA    [64][192] bf16 swz384 (24576) -> becomes AO after phase 3
//  maskL [64][68]  fp32 (17408)
//  Kh    6 x [64][32] bf16 swz64  (24576)
//  Vt    6 x [32][64] bf16 swz128 (24576)
#define OFF_MASK 24576
#define OFF_K    41984
#define OFF_V    66560
#define LDS_BYTES 91136

typedef __attribute__((ext_vector_type(8))) short bf16x8;
typedef __attribute__((ext_vector_type(4))) short bf16x4;
typedef __attribute__((ext_vector_type(4))) float f32x4;
typedef __attribute__((ext_vector_type(4))) unsigned int u32x4;

static __device__ __forceinline__ unsigned short f2b(float f) {
    __hip_bfloat16 h = __float2bfloat16(f);
    return __builtin_bit_cast(unsigned short, h);
}
static __device__ __forceinline__ char* swz384(char* base, int row, int b) {
    return base + ((row * 384 + b) ^ ((row & 7) << 4));
}
static __device__ __forceinline__ char* swz64(char* base, int row, int b) {
    return base + row * 64 + (b ^ (((row >> 1) & 3) << 4));
}
static __device__ __forceinline__ char* swz128(char* base, int row, int b) {
    return base + ((row * 128 + b) ^ ((row & 7) << 4));
}

// pack f32x4 (+bias) into one bf16 quad (2 dwords)
static __device__ __forceinline__ uint2 packq4(f32x4 v, float4 b) {
    unsigned short e0 = f2b(v[0] + b.x), e1 = f2b(v[1] + b.y);
    unsigned short e2 = f2b(v[2] + b.z), e3 = f2b(v[3] + b.w);
    uint2 q; q.x = (unsigned)e0 | ((unsigned)e1 << 16);
             q.y = (unsigned)e2 | ((unsigned)e3 << 16);
    return q;
}
static __device__ __forceinline__ uint2 packq0(f32x4 v) {
    unsigned short e0 = f2b(v[0]), e1 = f2b(v[1]);
    unsigned short e2 = f2b(v[2]), e3 = f2b(v[3]);
    uint2 q; q.x = (unsigned)e0 | ((unsigned)e1 << 16);
             q.y = (unsigned)e2 | ((unsigned)e3 << 16);
    return q;
}

// hi-group 4x4 quad transpose among lanes {lo, lo+16, lo+32, lo+48}.
static __device__ __forceinline__ void p8(uint2 a, uint2 b, int lo, int hi,
                                          uint2& oa, uint2& ob) {
    int sA = lo + ((hi & 1) << 5);
    int sB = sA + 16;
    uint2 Aa, Ab, Ba, Bb;
    Aa.x = (unsigned)__shfl((int)a.x, sA); Aa.y = (unsigned)__shfl((int)a.y, sA);
    Ab.x = (unsigned)__shfl((int)b.x, sA); Ab.y = (unsigned)__shfl((int)b.y, sA);
    Ba.x = (unsigned)__shfl((int)a.x, sB); Ba.y = (unsigned)__shfl((int)a.y, sB);
    Bb.x = (unsigned)__shfl((int)b.x, sB); Bb.y = (unsigned)__shfl((int)b.y, sB);
    oa = (hi < 2) ? Aa : Ab;
    ob = (hi < 2) ? Ba : Bb;
}
static __device__ __forceinline__ bf16x8 mkfrag(uint2 oa, uint2 ob) {
    u32x4 u; u[0] = oa.x; u[1] = oa.y; u[2] = ob.x; u[3] = ob.y;
    return __builtin_bit_cast(bf16x8, u);
}

// ---------------- prep: fp32 weights -> bf16 (scale folded into W_q) ----------------
__global__ __launch_bounds__(256)
void prep_weights(const float* __restrict__ qkv_w, const float* __restrict__ proj_w,
                  unsigned short* __restrict__ wq, unsigned short* __restrict__ wp)
{
    int i = blockIdx.x * 256 + threadIdx.x;
    if (i < WQ_ELEMS) {
        float v = qkv_w[i];
        if (i < CDIM * CDIM) v *= SCALE;
        wq[i] = f2b(v);
    }
    if (i < WP_ELEMS) wp[i] = f2b(proj_w[i]);
}

// ---------------- fused: block = window, 12 waves = (head, half) ----------------
__global__ __launch_bounds__(NTHR, 3)
void win_attn(const float* __restrict__ x,
              const float* __restrict__ mask,
              const unsigned short* __restrict__ wq,
              const float* __restrict__ qkv_b,
              const unsigned short* __restrict__ wp,
              const float* __restrict__ proj_b,
              const float* __restrict__ bias_table,
              float* __restrict__ out)
{
    extern __shared__ char smem[];
    char*  XA    = smem;
    float* maskL = (float*)(smem + OFF_MASK);

    const int t    = threadIdx.x;
    const int w    = blockIdx.x;
    const int wv   = t >> 6;
    const int h    = wv >> 1;       // head
    const int half = wv & 1;        // token half (0: n<32, 1: n>=32)
    const int l    = t & 63;
    const int lo   = l & 15;
    const int hi   = l >> 4;

    char* Kh = smem + OFF_K + h * 4096;   // [64 m][32 d] bf16 swz64
    char* Vh = smem + OFF_V + h * 4096;   // Vt [32 d][64 m] bf16 swz128

    // ---- phase 0: stage X (fp32->bf16 swz384) + mask ----
    const float* xw = x + (size_t)w * (NTOK * CDIM);
    #pragma unroll
    for (int it = 0; it < 2; ++it) {
        int c  = t + it * NTHR;            // 1536 chunks of 8 floats
        int n  = c / 24;
        int cb = (c % 24) * 8;
        float4 v0 = *(const float4*)(xw + c * 8);
        float4 v1 = *(const float4*)(xw + c * 8 + 4);
        bf16x8 p;
        p[0] = (short)f2b(v0.x); p[1] = (short)f2b(v0.y);
        p[2] = (short)f2b(v0.z); p[3] = (short)f2b(v0.w);
        p[4] = (short)f2b(v1.x); p[5] = (short)f2b(v1.y);
        p[6] = (short)f2b(v1.z); p[7] = (short)f2b(v1.w);
        *(bf16x8*)swz384(XA, n, cb * 2) = p;
    }
    const float* mw = mask + (size_t)w * (NTOK * NTOK);
    #pragma unroll
    for (int it = 0; it < 2; ++it) {
        int c = t + it * NTHR;             // 1024 float4
        if (c < 1024) {
            float4 v = *(const float4*)(mw + c * 4);
            *(float4*)(maskL + (c >> 4) * 68 + (c & 15) * 4) = v;
        }
    }
    __syncthreads();

    // ---- phase 1: wave produces Q (regs) + K,V (per-head LDS) for its 32 tokens ----
    const int tq = 2 * h, tk = 12 + 2 * h, tv = 24 + 2 * h;
    f32x4 aq[2][2] = {}, ak[2][2] = {}, av[2][2] = {};
    for (int ks = 0; ks < 6; ++ks) {
        bf16x8 xf[2];
        #pragma unroll
        for (int ntl = 0; ntl < 2; ++ntl)
            xf[ntl] = *(const bf16x8*)swz384(XA, (half * 2 + ntl) * 16 + lo,
                                             (ks * 32 + hi * 8) * 2);
        bf16x8 wqf[2], wkf[2], wvf[2];
        #pragma unroll
        for (int j = 0; j < 2; ++j) {
            wqf[j] = *(const bf16x8*)(const void*)(wq + ((tq + j) * 16 + lo) * CDIM + ks * 32 + hi * 8);
            wkf[j] = *(const bf16x8*)(const void*)(wq + ((tk + j) * 16 + lo) * CDIM + ks * 32 + hi * 8);
            wvf[j] = *(const bf16x8*)(const void*)(wq + ((tv + j) * 16 + lo) * CDIM + ks * 32 + hi * 8);
        }
        #pragma unroll
        for (int j = 0; j < 2; ++j)
            #pragma unroll
            for (int ntl = 0; ntl < 2; ++ntl) {
                aq[j][ntl] = __builtin_amdgcn_mfma_f32_16x16x32_bf16(wqf[j], xf[ntl], aq[j][ntl], 0, 0, 0);
                ak[j][ntl] = __builtin_amdgcn_mfma_f32_16x16x32_bf16(wkf[j], xf[ntl], ak[j][ntl], 0, 0, 0);
                av[ntl][j] = __builtin_amdgcn_mfma_f32_16x16x32_bf16(xf[ntl], wvf[j], av[ntl][j], 0, 0, 0);
            }
    }

    // Q -> register B-frags (p8 transpose), scale folded
    bf16x8 Qf[2];
    {
        float4 bq0 = *(const float4*)(qkv_b + tq * 16 + hi * 4);
        float4 bq1 = *(const float4*)(qkv_b + (tq + 1) * 16 + hi * 4);
        bq0.x *= SCALE; bq0.y *= SCALE; bq0.z *= SCALE; bq0.w *= SCALE;
        bq1.x *= SCALE; bq1.y *= SCALE; bq1.z *= SCALE; bq1.w *= SCALE;
        #pragma unroll
        for (int ntl = 0; ntl < 2; ++ntl) {
            uint2 oa, ob;
            p8(packq4(aq[0][ntl], bq0), packq4(aq[1][ntl], bq1), lo, hi, oa, ob);
            Qf[ntl] = mkfrag(oa, ob);
        }
    }
    // K -> LDS [m][d] (packed b64). D rows o=d=j*16+hi*4+r, cols m=16*(2half+mtl)+lo
    #pragma unroll
    for (int j = 0; j < 2; ++j) {
        float4 bk = *(const float4*)(qkv_b + (tk + j) * 16 + hi * 4);
        float bkr[4] = {bk.x, bk.y, bk.z, bk.w};
        #pragma unroll
        for (int mtl = 0; mtl < 2; ++mtl) {
            int m = (half * 2 + mtl) * 16 + lo;
            bf16x4 pk;
            #pragma unroll
            for (int r = 0; r < 4; ++r) pk[r] = (short)f2b(ak[j][mtl][r] + bkr[r]);
            *(bf16x4*)swz64(Kh, m, j * 32 + hi * 8) = pk;
        }
    }
    // V -> LDS Vt [d][m] (packed b64). D rows n(=m)=16*(2half+mtl)+hi*4+r, cols d=j*16+lo
    #pragma unroll
    for (int mtl = 0; mtl < 2; ++mtl)
        #pragma unroll
        for (int j = 0; j < 2; ++j) {
            float bv = qkv_b[(tv + j) * 16 + lo];
            bf16x4 pv;
            #pragma unroll
            for (int r = 0; r < 4; ++r) pv[r] = (short)f2b(av[mtl][j][r] + bv);
            *(bf16x4*)swz128(Vh, j * 16 + lo, ((half * 2 + mtl) * 16 + hi * 4) * 2) = pv;
        }
    __syncthreads();

    // ---- phase 2: S^T = K.Q^T + bias + mask (C-init). cs[mt][ntl], n = 16(2half+ntl)+lo ----
    bf16x8 Kf[4];
    #pragma unroll
    for (int mt = 0; mt < 4; ++mt)
        Kf[mt] = *(const bf16x8*)swz64(Kh, mt * 16 + lo, hi * 16);

    f32x4 cs[4][2];
    #pragma unroll
    for (int ntl = 0; ntl < 2; ++ntl) {
        int n  = (half * 2 + ntl) * 16 + lo;
        int i1 = n >> 3, j1 = n & 7;
        #pragma unroll
        for (int mt = 0; mt < 4; ++mt) {
            float4 mv = *(const float4*)(maskL + n * 68 + mt * 16 + hi * 4);
            float mvr[4] = {mv.x, mv.y, mv.z, mv.w};
            #pragma unroll
            for (int r = 0; r < 4; ++r) {
                int m  = mt * 16 + hi * 4 + r;
                int i2 = m >> 3, j2 = m & 7;
                cs[mt][ntl][r] = bias_table[((i1 - i2 + 7) * 15 + (j1 - j2 + 7)) * HEADS + h]
                               + mvr[r];
            }
        }
    }
    #pragma unroll
    for (int mt = 0; mt < 4; ++mt)
        #pragma unroll
        for (int ntl = 0; ntl < 2; ++ntl)
            cs[mt][ntl] = __builtin_amdgcn_mfma_f32_16x16x32_bf16(Kf[mt], Qf[ntl], cs[mt][ntl], 0, 0, 0);

    // ---- softmax over m (per column n); fold 1/sum; transpose to A-frags ----
    bf16x8 Pf[2][2];
    #pragma unroll
    for (int ntl = 0; ntl < 2; ++ntl) {
        float mx = cs[0][ntl][0];
        #pragma unroll
        for (int mt = 0; mt < 4; ++mt)
            #pragma unroll
            for (int r = 0; r < 4; ++r) mx = fmaxf(mx, cs[mt][ntl][r]);
        mx = fmaxf(mx, __shfl_xor(mx, 16));
        mx = fmaxf(mx, __shfl_xor(mx, 32));
        float s = 0.f;
        #pragma unroll
        for (int mt = 0; mt < 4; ++mt)
            #pragma unroll
            for (int r = 0; r < 4; ++r) {
                float e = __expf(cs[mt][ntl][r] - mx);
                cs[mt][ntl][r] = e;
                s += e;
            }
        s += __shfl_xor(s, 16);
        s += __shfl_xor(s, 32);
        float iv = 1.0f / s;
        #pragma unroll
        for (int mt = 0; mt < 4; ++mt)
            #pragma unroll
            for (int r = 0; r < 4; ++r) cs[mt][ntl][r] *= iv;
        uint2 oa, ob;
        p8(packq0(cs[0][ntl]), packq0(cs[1][ntl]), lo, hi, oa, ob);
        Pf[0][ntl] = mkfrag(oa, ob);
        p8(packq0(cs[2][ntl]), packq0(cs[3][ntl]), lo, hi, oa, ob);
        Pf[1][ntl] = mkfrag(oa, ob);
    }

    // ---- phase 3: O = P.V ----
    f32x4 co[2][2] = {};
    #pragma unroll
    for (int ks = 0; ks < 2; ++ks) {
        bf16x8 vb[2];
        #pragma unroll
        for (int dt = 0; dt < 2; ++dt)
            vb[dt] = *(const bf16x8*)swz128(Vh, dt * 16 + lo, (ks * 32 + hi * 8) * 2);
        #pragma unroll
        for (int ntl = 0; ntl < 2; ++ntl)
            #pragma unroll
            for (int dt = 0; dt < 2; ++dt)
                co[ntl][dt] = __builtin_amdgcn_mfma_f32_16x16x32_bf16(Pf[ks][ntl], vb[dt], co[ntl][dt], 0, 0, 0);
    }
    // AO overlays X (all X reads finished before barrier #2)
    #pragma unroll
    for (int ntl = 0; ntl < 2; ++ntl)
        #pragma unroll
        for (int dt = 0; dt < 2; ++dt)
            #pragma unroll
            for (int r = 0; r < 4; ++r) {
                int n = (half * 2 + ntl) * 16 + hi * 4 + r;
                *(unsigned short*)swz384(XA, n, (h * 32 + dt * 16 + lo) * 2) =
                    f2b(co[ntl][dt][r]);
            }
    __syncthreads();

    // ---- phase 4: out = AO . Wp^T + b (wave owns o-tile wv) ----
    f32x4 ac[4] = {};
    const int o2 = wv * 16 + lo;
    for (int ks = 0; ks < 6; ++ks) {
        bf16x8 bb = *(const bf16x8*)(const void*)(wp + o2 * CDIM + ks * 32 + hi * 8);
        #pragma unroll
        for (int nt = 0; nt < 4; ++nt) {
            bf16x8 aa = *(const bf16x8*)swz384(XA, nt * 16 + lo, (ks * 32 + hi * 8) * 2);
            ac[nt] = __builtin_amdgcn_mfma_f32_16x16x32_bf16(aa, bb, ac[nt], 0, 0, 0);
        }
    }
    float* outW = out + (size_t)w * (NTOK * CDIM);
    float pb = proj_b[o2];
    #pragma unroll
    for (int nt = 0; nt < 4; ++nt)
        #pragma unroll
        for (int r = 0; r < 4; ++r) {
            int n = nt * 16 + hi * 4 + r;
            outW[n * CDIM + o2] = ac[nt][r] + pb;
        }
}

extern "C" void kernel_launch(void* const* d_in, const int* in_sizes, int n_in,
                              void* d_out, int out_size, void* d_ws, size_t ws_size,
                              hipStream_t stream) {
    const float* x          = (const float*)d_in[0];
    const float* mask       = (const float*)d_in[1];
    const float* qkv_w      = (const float*)d_in[2];
    const float* qkv_b      = (const float*)d_in[3];
    const float* proj_w     = (const float*)d_in[4];
    const float* proj_b     = (const float*)d_in[5];
    const float* bias_table = (const float*)d_in[6];
    float* out = (float*)d_out;

    unsigned short* wq = (unsigned short*)d_ws;
    unsigned short* wp = wq + WQ_ELEMS;

    const int nW = in_sizes[0] / (NTOK * CDIM);   // 4096

    prep_weights<<<dim3((WQ_ELEMS + 255) / 256), dim3(256), 0, stream>>>(qkv_w, proj_w, wq, wp);

    hipFuncSetAttribute(reinterpret_cast<const void*>(win_attn),
                        hipFuncAttributeMaxDynamicSharedMemorySize, LDS_BYTES);
    win_attn<<<dim3(nW), dim3(NTHR), LDS_BYTES, stream>>>(x, mask, wq, qkv_b, wp,
                                                          proj_b, bias_table, out);
}